// Round 9
// baseline (227.017 us; speedup 1.0000x reference)
//
#include <hip/hip_runtime.h>
#include <hip/hip_bf16.h>
#include <stdint.h>

#define DEVINL __device__ __forceinline__

using bf16x8 = __attribute__((ext_vector_type(8))) short;
using f32x4  = __attribute__((ext_vector_type(4))) float;

static constexpr int NPTS = 50000;
static constexpr int NPAD = 50176;         // 196 * 256
static constexpr int DIM  = 768;
static constexpr int DATT = 128;
static constexpr int NRB  = NPAD / 128;    // 392 row blocks (gate / partial)
static constexpr int NSMB = 49;            // softmax partial blocks

DEVINL ushort f2b(float f) {               // RNE float->bf16 (finite inputs)
  uint32_t u = __float_as_uint(f);
  u += 0x7fffu + ((u >> 16) & 1u);
  return (ushort)(u >> 16);
}
DEVINL float b2f(ushort u) { return __uint_as_float(((uint32_t)u) << 16); }

DEVINL void gload_lds16(const void* g, void* l) {
  __builtin_amdgcn_global_load_lds((const __attribute__((address_space(1))) void*)g,
                                   (__attribute__((address_space(3))) void*)l,
                                   16, 0, 0);
}

// ---------------- K0a: fp32 -> bf16 convert of x (8 elems/thread), zero-pads --
__global__ void cvt8_kernel(const float* __restrict__ src, ushort* __restrict__ dst,
                            int n8_src, int n8_dst) {
  const int stride = gridDim.x * blockDim.x;
  for (int i = blockIdx.x * blockDim.x + threadIdx.x; i < n8_dst; i += stride) {
    float4 v0 = {0.f, 0.f, 0.f, 0.f}, v1 = {0.f, 0.f, 0.f, 0.f};
    if (i < n8_src) {
      const float4* s4 = (const float4*)src;
      v0 = s4[(long)i * 2];
      v1 = s4[(long)i * 2 + 1];
    }
    ushort4 o0 = { f2b(v0.x), f2b(v0.y), f2b(v0.z), f2b(v0.w) };
    ushort4 o1 = { f2b(v1.x), f2b(v1.y), f2b(v1.z), f2b(v1.w) };
    ((ushort4*)dst)[(long)i * 2]     = o0;
    ((ushort4*)dst)[(long)i * 2 + 1] = o1;
  }
}

// ---------------- K0b: fp32 -> bf16 for the three weight matrices -------------
__global__ void cvt_weights_kernel(const float* __restrict__ Wf, const float* __restrict__ Wa,
                                   const float* __restrict__ Wb,
                                   ushort* __restrict__ wfb, ushort* __restrict__ wab,
                                   ushort* __restrict__ wbb) {
  const int NF = DIM * DIM / 8, NA = DATT * DIM / 8;
  int i = blockIdx.x * blockDim.x + threadIdx.x;
  const float* src; ushort* dst; int j;
  if (i < NF)               { src = Wf; dst = wfb; j = i; }
  else if (i < NF + NA)     { src = Wa; dst = wab; j = i - NF; }
  else if (i < NF + 2 * NA) { src = Wb; dst = wbb; j = i - NF - NA; }
  else return;
  const float4* s4 = (const float4*)src;
  float4 v0 = s4[(long)j * 2];
  float4 v1 = s4[(long)j * 2 + 1];
  ushort4 o0 = { f2b(v0.x), f2b(v0.y), f2b(v0.z), f2b(v0.w) };
  ushort4 o1 = { f2b(v1.x), f2b(v1.y), f2b(v1.z), f2b(v1.w) };
  ((ushort4*)dst)[(long)j * 2]     = o0;
  ((ushort4*)dst)[(long)j * 2 + 1] = o1;
}

// ---------------- K1: h = relu(x @ Wf^T + bias) — phase-rotated deep pipeline -
// BM=BN=256, BK=32, 24 K-tiles. 8 waves (2M x 4N), wave tile 128x64.
// 4 LDS buffers x (A 16KB + B 16KB) = 128KB. Per K-tile 2 phases (C-half 0/1):
//   vmcnt(4) -> s_barrier -> 8x ds_read_b128 -> stage 16KB tile of t+2
//   (A at ch=0, B at ch=1; 2 gload_lds/thread) -> sched_barrier ->
//   setprio(1) 16 MFMA setprio(0)
// Wait arithmetic (FIFO retire): per-phase vmcnt(4) => landed through phase
// p-3; first reads: A staged p-4, B staged p-3 -> safe. Tail: vmcnt(0) at t=23.
// Stage target buf[(t+2)&3] is disjoint from buf[t&3]/buf[(t+1)&3] readers.
// LDS layout: pair-interleaved 8-slot XOR — row r chunk j (8 bf16) at byte
// (r>>1)*128 + (((j + 4*(r&1)) ^ ((r>>1)&7))<<4) — replicates R8's
// measured-zero-conflict density. Stage: linear dest, pre-permuted source.
__global__ __launch_bounds__(512)
void gemm_h_kernel(const ushort* __restrict__ A, const ushort* __restrict__ B,
                   const float* __restrict__ bias, ushort* __restrict__ H) {
  __shared__ __align__(16) char lds[4][32768];   // per buf: A @0 (16KB), B @16384

  const int tid  = threadIdx.x;
  const int wid  = tid >> 6;           // 0..7
  const int lane = tid & 63;

  // bijective XCD swizzle, nwg=588: q=73, r=4 (m204)
  const int bid = blockIdx.x;
  const int xcd = bid & 7, idx = bid >> 3;
  const int wgid = (xcd < 4 ? xcd * 74 : 4 * 74 + (xcd - 4) * 73) + idx;
  const int row0 = (wgid / 3) * 256;
  const int col0 = (wgid % 3) * 256;

  const ushort* Abase = A + (long)row0 * DIM;
  const ushort* Bbase = B + (long)col0 * DIM;

  // staging geometry: lane l writes 16B to linear dest base + l*16.
  // dest (pair rp, slot s=l&7) holds logical row r = rp*2 + (pre>>2),
  // k-chunk c = pre&3 where pre = s ^ (rp&7). Since rp&7 == lane>>3:
  const int pre = (lane & 7) ^ (lane >> 3);
  const int sr0 = wid * 16 + ((lane >> 3) << 1) + (pre >> 2);  // row within 128
  const int sc0 = (pre & 3) * 8;                               // bf16 col within 32

  auto STAGE_A = [&](int tt) {
    const int buf = tt & 3;
    const long k0 = (long)tt * 32;
#pragma unroll
    for (int i = 0; i < 2; ++i)
      gload_lds16(Abase + (long)(i * 128 + sr0) * DIM + k0 + sc0,
                  &lds[buf][(i * 64 + wid * 8) * 128]);
  };
  auto STAGE_B = [&](int tt) {
    const int buf = tt & 3;
    const long k0 = (long)tt * 32;
#pragma unroll
    for (int i = 0; i < 2; ++i)
      gload_lds16(Bbase + (long)(i * 128 + sr0) * DIM + k0 + sc0,
                  &lds[buf][16384 + (i * 64 + wid * 8) * 128]);
  };

  f32x4 acc0[4][4] = {};   // C-half 0 (wave rows 0..63)
  f32x4 acc1[4][4] = {};   // C-half 1 (wave rows 64..127)

  const int wrbase = (wid >> 2) * 128;   // wave A-row base (0 or 128)
  const int wcbase = (wid & 3) * 64;     // wave B-row (C-col) base

  auto PHASE = [&](int t, int ch, f32x4 (&ac)[4][4]) {
    const int buf = t & 3;
    const ushort* Ab = (const ushort*)&lds[buf][0];
    const ushort* Bb = (const ushort*)&lds[buf][16384];
    const int j = lane >> 4;             // k-chunk 0..3
    bf16x8 a[4], b[4];
#pragma unroll
    for (int fm = 0; fm < 4; ++fm) {
      const int ra = wrbase + ch * 64 + fm * 16 + (lane & 15);
      const int pr = ra >> 1;
      const int sl = (j + 4 * (ra & 1)) ^ (pr & 7);
      a[fm] = *(const bf16x8*)(Ab + pr * 64 + sl * 8);
    }
#pragma unroll
    for (int fn = 0; fn < 4; ++fn) {
      const int rb = wcbase + fn * 16 + (lane & 15);
      const int pr = rb >> 1;
      const int sl = (j + 4 * (rb & 1)) ^ (pr & 7);
      b[fn] = *(const bf16x8*)(Bb + pr * 64 + sl * 8);
    }
    if (t < 22) { if (ch == 0) STAGE_A(t + 2); else STAGE_B(t + 2); }
    __builtin_amdgcn_sched_barrier(0);
    __builtin_amdgcn_s_setprio(1);
#pragma unroll
    for (int fn = 0; fn < 4; ++fn)
#pragma unroll
      for (int fm = 0; fm < 4; ++fm)
        ac[fm][fn] = __builtin_amdgcn_mfma_f32_16x16x32_bf16(a[fm], b[fn], ac[fm][fn], 0, 0, 0);
    __builtin_amdgcn_s_setprio(0);
    __builtin_amdgcn_sched_barrier(0);
  };

  // prologue: tiles 0 and 1, in steady-state issue order A,B,A,B
  STAGE_A(0); STAGE_B(0); STAGE_A(1); STAGE_B(1);

#pragma unroll 1
  for (int t = 0; t < 24; ++t) {
    if (t < 23) asm volatile("s_waitcnt vmcnt(4)" ::: "memory");
    else        asm volatile("s_waitcnt vmcnt(0)" ::: "memory");
    __builtin_amdgcn_s_barrier();
    PHASE(t, 0, acc0);
    if (t < 23) asm volatile("s_waitcnt vmcnt(4)" ::: "memory");
    else        asm volatile("s_waitcnt vmcnt(0)" ::: "memory");
    __builtin_amdgcn_s_barrier();
    PHASE(t, 1, acc1);
  }

  // epilogue: bias + relu + bf16 store
  const int lq = lane >> 4;
  const int lc = lane & 15;
#pragma unroll
  for (int fn = 0; fn < 4; ++fn) {
    const int cg = col0 + wcbase + fn * 16 + lc;
    const float bv = bias[cg];
#pragma unroll
    for (int fm = 0; fm < 4; ++fm) {
      const int rg0 = row0 + wrbase + fm * 16 + lq * 4;
#pragma unroll
      for (int r2 = 0; r2 < 4; ++r2) {
        float v0 = acc0[fm][fn][r2] + bv;
        H[(long)(rg0 + r2) * DIM + cg] = f2b(fmaxf(v0, 0.0f));
        float v1 = acc1[fm][fn][r2] + bv;
        H[(long)(rg0 + 64 + r2) * DIM + cg] = f2b(fmaxf(v1, 0.0f));
      }
    }
  }
}

// ---------------- K2: logits[n] = sum_k relu(h·Wa^T)·sigmoid(h·Wb^T)·Wc -------
__global__ __launch_bounds__(512)
void gate_kernel(const ushort* __restrict__ Hm, const ushort* __restrict__ Wa,
                 const ushort* __restrict__ Wb, const float* __restrict__ Wc,
                 float* __restrict__ logits) {
  __shared__ ushort Hs [128 * 64];
  __shared__ ushort Was[128 * 64];
  __shared__ ushort Wbs[128 * 64];
  const int tid  = threadIdx.x;
  const int wid  = tid >> 6;           // 0..7
  const int lane = tid & 63;
  const int row0 = blockIdx.x * 128;

  f32x4 fa[8] = {};
  f32x4 fb[8] = {};

  const int ld_r = lane >> 3;
  const int ld_c = (lane & 7) * 8;

  for (int k0 = 0; k0 < DIM; k0 += 64) {
    __syncthreads();
#pragma unroll
    for (int i = 0; i < 2; ++i) {
      const int ch = i * 8 + wid;      // 0..15
      const int r  = ch * 8 + ld_r;    // 0..127
      gload_lds16(Hm + (long)(row0 + r) * DIM + k0 + ld_c, Hs  + ch * 512);
      gload_lds16(Wa + (long)r * DIM        + k0 + ld_c, Was + ch * 512);
      gload_lds16(Wb + (long)r * DIM        + k0 + ld_c, Wbs + ch * 512);
    }
    __syncthreads();
#pragma unroll
    for (int kk = 0; kk < 2; ++kk) {
      const int kc = kk * 32 + (lane >> 4) * 8;
      bf16x8 h = *(const bf16x8*)(Hs + (wid * 16 + (lane & 15)) * 64 + kc);
#pragma unroll
      for (int n = 0; n < 8; ++n) {
        bf16x8 wa = *(const bf16x8*)(Was + (n * 16 + (lane & 15)) * 64 + kc);
        bf16x8 wb = *(const bf16x8*)(Wbs + (n * 16 + (lane & 15)) * 64 + kc);
        fa[n] = __builtin_amdgcn_mfma_f32_16x16x32_bf16(h, wa, fa[n], 0, 0, 0);
        fb[n] = __builtin_amdgcn_mfma_f32_16x16x32_bf16(h, wb, fb[n], 0, 0, 0);
      }
    }
  }

  const int lc = lane & 15;
  const int lq = lane >> 4;
  float g[4];
#pragma unroll
  for (int r = 0; r < 4; ++r) {
    float s = 0.f;
#pragma unroll
    for (int n = 0; n < 8; ++n) {
      float av = fmaxf(fa[n][r], 0.f);
      float sg = 1.f / (1.f + expf(-fb[n][r]));
      s += av * sg * Wc[n * 16 + lc];
    }
    s += __shfl_xor(s, 1);
    s += __shfl_xor(s, 2);
    s += __shfl_xor(s, 4);
    s += __shfl_xor(s, 8);
    g[r] = s;
  }
  if (lc == 0) {
    const int rbase = row0 + wid * 16 + lq * 4;
#pragma unroll
    for (int r = 0; r < 4; ++r) {
      const int nidx = rbase + r;
      if (nidx < NPTS) logits[nidx] = g[r];
    }
  }
}

// ---------------- K3a: per-block softmax partials (49 blocks x 1024) ----------
__global__ __launch_bounds__(1024)
void softmax_part_kernel(const float* __restrict__ logits, float* __restrict__ part2) {
  __shared__ float red[1024];
  const int tid = threadIdx.x;
  const int n = blockIdx.x * 1024 + tid;
  const float v = (n < NPTS) ? logits[n] : -1e30f;
  red[tid] = v; __syncthreads();
  for (int s = 512; s > 0; s >>= 1) {
    if (tid < s) red[tid] = fmaxf(red[tid], red[tid + s]);
    __syncthreads();
  }
  const float m = red[0];
  __syncthreads();
  red[tid] = (n < NPTS) ? expf(v - m) : 0.f;
  __syncthreads();
  for (int s = 512; s > 0; s >>= 1) {
    if (tid < s) red[tid] += red[tid + s];
    __syncthreads();
  }
  if (tid == 0) { part2[blockIdx.x * 2] = m; part2[blockIdx.x * 2 + 1] = red[0]; }
}

// ---------------- K3b: combine partials (1 wave, deterministic trees) ---------
__global__ void softmax_comb_kernel(const float* __restrict__ part2,
                                    float* __restrict__ stats) {
  const int l = threadIdx.x;           // 0..63
  float m = (l < NSMB) ? part2[l * 2]     : -1e30f;
  float s = (l < NSMB) ? part2[l * 2 + 1] : 0.f;
  float M = m;
  for (int o = 32; o > 0; o >>= 1) M = fmaxf(M, __shfl_xor(M, o));
  float sc = s * expf(m - M);          // padding: 0 * 0 = 0
  for (int o = 32; o > 0; o >>= 1) sc += __shfl_xor(sc, o);
  if (l == 0) { stats[0] = M; stats[1] = sc; }
}

// ---------------- K4: partial[b][d] = sum_{n in chunk} exp(l_n - m) * h[n][d] --
__global__ __launch_bounds__(192)
void weighted_partial_kernel(const ushort* __restrict__ Hm, const float* __restrict__ logits,
                             const float* __restrict__ stats, float* __restrict__ part) {
  __shared__ float w[128];
  const int b = blockIdx.x, tid = threadIdx.x;
  const int n0 = b * 128;
  if (tid < 128) {
    const int n = n0 + tid;
    w[tid] = (n < NPTS) ? expf(logits[n] - stats[0]) : 0.f;
  }
  __syncthreads();
  float4 acc = {0.f, 0.f, 0.f, 0.f};
  const ushort* hp = Hm + (long)n0 * DIM + tid * 4;
#pragma unroll 4
  for (int r = 0; r < 128; ++r) {
    const float wr = w[r];
    ushort4 v = *(const ushort4*)(hp + (long)r * DIM);
    acc.x += wr * b2f(v.x);
    acc.y += wr * b2f(v.y);
    acc.z += wr * b2f(v.z);
    acc.w += wr * b2f(v.w);
  }
  ((float4*)(part + (long)b * DIM))[tid] = acc;
}

// ---------------- K5: out[d] = (sum_b part[b][d]) / sum_exp --------------------
__global__ void final_reduce_kernel(const float* __restrict__ part,
                                    const float* __restrict__ stats,
                                    float* __restrict__ out) {
  const int c = blockIdx.x * blockDim.x + threadIdx.x;
  if (c >= DIM) return;
  float s = 0.f;
  for (int b = 0; b < NRB; ++b) s += part[(long)b * DIM + c];
  out[c] = s / stats[1];
}

extern "C" void kernel_launch(void* const* d_in, const int* in_sizes, int n_in,
                              void* d_out, int out_size, void* d_ws, size_t ws_size,
                              hipStream_t stream) {
  const float* x  = (const float*)d_in[0];
  const float* Wf = (const float*)d_in[1];
  const float* bf = (const float*)d_in[2];
  const float* Wa = (const float*)d_in[3];
  const float* Wb = (const float*)d_in[4];
  const float* Wc = (const float*)d_in[5];
  float* out = (float*)d_out;

  char* p = (char*)d_ws;
  ushort* xb  = (ushort*)p; p += (size_t)NPAD * DIM * 2;   // 77.1 MB
  ushort* hb  = (ushort*)p; p += (size_t)NPAD * DIM * 2;   // 77.1 MB
  ushort* wfb = (ushort*)p; p += (size_t)DIM * DIM * 2;
  ushort* wab = (ushort*)p; p += (size_t)DATT * DIM * 2;
  ushort* wbb = (ushort*)p; p += (size_t)DATT * DIM * 2;
  float* logits = (float*)p; p += (size_t)NPAD * 4;
  float* stats  = (float*)p; p += 256;
  float* part2  = (float*)p; p += 1024;
  float* part   = (float*)p; p += (size_t)NRB * DIM * 4;

  cvt8_kernel<<<2048, 256, 0, stream>>>(x, xb, NPTS * DIM / 8, NPAD * DIM / 8);
  cvt_weights_kernel<<<384, 256, 0, stream>>>(Wf, Wa, Wb, wfb, wab, wbb);

  gemm_h_kernel<<<196 * 3, 512, 0, stream>>>(xb, wfb, bf, hb);
  gate_kernel<<<NRB, 512, 0, stream>>>(hb, wab, wbb, Wc, logits);
  softmax_part_kernel<<<NSMB, 1024, 0, stream>>>(logits, part2);
  softmax_comb_kernel<<<1, 64, 0, stream>>>(part2, stats);
  weighted_partial_kernel<<<NRB, 192, 0, stream>>>(hb, logits, stats, part);
  final_reduce_kernel<<<3, 256, 0, stream>>>(part, stats, out);
}

// Round 10
// 221.587 us; speedup vs baseline: 1.0245x; 1.0245x over previous
//
#include <hip/hip_runtime.h>
#include <hip/hip_bf16.h>
#include <stdint.h>

#define DEVINL __device__ __forceinline__

using bf16x8 = __attribute__((ext_vector_type(8))) short;
using f32x4  = __attribute__((ext_vector_type(4))) float;

static constexpr int NPTS = 50000;
static constexpr int NPAD = 50176;         // 196 * 256
static constexpr int DIM  = 768;
static constexpr int DATT = 128;
static constexpr int NRB  = NPAD / 128;    // 392 row blocks (gate / partial)
static constexpr int NSMB = 49;            // softmax partial blocks

DEVINL ushort f2b(float f) {               // RNE float->bf16 (finite inputs)
  uint32_t u = __float_as_uint(f);
  u += 0x7fffu + ((u >> 16) & 1u);
  return (ushort)(u >> 16);
}
DEVINL float b2f(ushort u) { return __uint_as_float(((uint32_t)u) << 16); }

DEVINL void gload_lds16(const void* g, void* l) {
  __builtin_amdgcn_global_load_lds((const __attribute__((address_space(1))) void*)g,
                                   (__attribute__((address_space(3))) void*)l,
                                   16, 0, 0);
}

// ---------------- K0a: fp32 -> bf16 convert of x (8 elems/thread), zero-pads --
__global__ void cvt8_kernel(const float* __restrict__ src, ushort* __restrict__ dst,
                            int n8_src, int n8_dst) {
  const int stride = gridDim.x * blockDim.x;
  for (int i = blockIdx.x * blockDim.x + threadIdx.x; i < n8_dst; i += stride) {
    float4 v0 = {0.f, 0.f, 0.f, 0.f}, v1 = {0.f, 0.f, 0.f, 0.f};
    if (i < n8_src) {
      const float4* s4 = (const float4*)src;
      v0 = s4[(long)i * 2];
      v1 = s4[(long)i * 2 + 1];
    }
    ushort4 o0 = { f2b(v0.x), f2b(v0.y), f2b(v0.z), f2b(v0.w) };
    ushort4 o1 = { f2b(v1.x), f2b(v1.y), f2b(v1.z), f2b(v1.w) };
    ((ushort4*)dst)[(long)i * 2]     = o0;
    ((ushort4*)dst)[(long)i * 2 + 1] = o1;
  }
}

// ---------------- K0b: fp32 -> bf16 for the three weight matrices -------------
__global__ void cvt_weights_kernel(const float* __restrict__ Wf, const float* __restrict__ Wa,
                                   const float* __restrict__ Wb,
                                   ushort* __restrict__ wfb, ushort* __restrict__ wab,
                                   ushort* __restrict__ wbb) {
  const int NF = DIM * DIM / 8, NA = DATT * DIM / 8;
  int i = blockIdx.x * blockDim.x + threadIdx.x;
  const float* src; ushort* dst; int j;
  if (i < NF)               { src = Wf; dst = wfb; j = i; }
  else if (i < NF + NA)     { src = Wa; dst = wab; j = i - NF; }
  else if (i < NF + 2 * NA) { src = Wb; dst = wbb; j = i - NF - NA; }
  else return;
  const float4* s4 = (const float4*)src;
  float4 v0 = s4[(long)j * 2];
  float4 v1 = s4[(long)j * 2 + 1];
  ushort4 o0 = { f2b(v0.x), f2b(v0.y), f2b(v0.z), f2b(v0.w) };
  ushort4 o1 = { f2b(v1.x), f2b(v1.y), f2b(v1.z), f2b(v1.w) };
  ((ushort4*)dst)[(long)j * 2]     = o0;
  ((ushort4*)dst)[(long)j * 2 + 1] = o1;
}

// ---------------- K1: h = relu(x @ Wf^T + bias) — 8-phase schedule ------------
// BM=BN=256, BK=64, 12 K-tiles = 6 iterations x 8 phases. 8 waves (2M x 4N),
// wave tile 128x64. LDS: 2 dbuf x (A[256][64] 32KB + B[256][64] 32KB) = 128KB.
// Phase = quadrant (m-half mh, kk): 8x ds_read_b128 -> optional stage (4x
// gload_lds, one operand of a future tile) -> lgkmcnt(0)+sched_barrier ->
// setprio(1) 16 MFMA setprio(0). Barrier at every phase entry.
// Stage/wait schedule (write-window verified):
//   phases 1-2: stage tile 2i+1 -> dbuf1 (read at phases 5-8; dbuf1's prior
//               reads ended last iter phase 8, fenced by phase-1 barrier)
//   phases 5-6: stage tile 2i+2 -> dbuf0 (read next iter phases 1-4)
//   vmcnt(0) ONLY at phase-1/5 entries: everything outstanding has been in
//   flight >= 2.5 phases -> drain is cheap (the R9 mistake was per-phase waits)
// LDS layout: R8's measured-zero-conflict 8-slot XOR (row r, chunk j at
// ushort off r*64 + ((j^(r&7))<<3)); staging = linear dest + pre-permuted src.
__global__ __launch_bounds__(512)
void gemm_h_kernel(const ushort* __restrict__ A, const ushort* __restrict__ B,
                   const float* __restrict__ bias, ushort* __restrict__ H) {
  __shared__ __align__(16) char lds[2][65536];   // per dbuf: A @0, B @32768

  const int tid  = threadIdx.x;
  const int wid  = tid >> 6;           // 0..7
  const int lane = tid & 63;

  // bijective XCD swizzle, nwg=588: q=73, r=4 (m204)
  const int bid = blockIdx.x;
  const int xcd = bid & 7, idx = bid >> 3;
  const int wgid = (xcd < 4 ? xcd * 74 : 4 * 74 + (xcd - 4) * 73) + idx;
  const int row0 = (wgid / 3) * 256;
  const int col0 = (wgid % 3) * 256;

  const int wrbase = (wid >> 2) * 128;   // wave A-row base (0 or 128)
  const int wcbase = (wid & 3) * 64;     // wave B-row (C-col) base

  const ushort* Abase = A + (long)row0 * DIM;
  const ushort* Bbase = B + (long)col0 * DIM;

  // staging source permutation (R8-verified): lane l writes 16B to linear dest
  // chunk_base + l*16; source row/col chosen so the XOR-swizzled read formula
  // finds row r chunk j at r*64 + ((j^(r&7))<<3).
  const int srow = lane >> 3;                          // 0..7
  const int scol = ((lane & 7) ^ (lane >> 3)) * 8;     // pre-swizzled col chunk

  auto STAGE_A = [&](int t, int d) {     // full A operand: 4 gload_lds (32KB)
    const long k0 = (long)t * 64;
#pragma unroll
    for (int i = 0; i < 4; ++i) {
      const int ch = i * 8 + wid;                      // 0..31, 8 rows each
      gload_lds16(Abase + (long)(ch * 8 + srow) * DIM + k0 + scol,
                  &lds[d][ch * 1024]);
    }
  };
  auto STAGE_B = [&](int t, int d) {     // full B operand: 4 gload_lds (32KB)
    const long k0 = (long)t * 64;
#pragma unroll
    for (int i = 0; i < 4; ++i) {
      const int ch = i * 8 + wid;
      gload_lds16(Bbase + (long)(ch * 8 + srow) * DIM + k0 + scol,
                  &lds[d][32768 + ch * 1024]);
    }
  };

  f32x4 acc0[4][4] = {};   // m-frags 0..3 (wave rows 0..63)
  f32x4 acc1[4][4] = {};   // m-frags 4..7 (wave rows 64..127)

  // one quadrant-phase: mh/kk select; stage_sel: 0 none, 1 A, 2 B (-> dbuf d^1)
  auto QPHASE = [&](int d, f32x4 (&ac)[4][4], int mh, int kk,
                    int stage_sel, int stage_t) {
    const ushort* Ab = (const ushort*)&lds[d][0];
    const ushort* Bb = (const ushort*)&lds[d][32768];
    const int j = kk * 4 + (lane >> 4);                // k-chunk
    bf16x8 a[4], b[4];
#pragma unroll
    for (int m = 0; m < 4; ++m) {
      const int ra = wrbase + mh * 64 + m * 16 + (lane & 15);
      a[m] = *(const bf16x8*)(Ab + ra * 64 + ((j ^ (ra & 7)) << 3));
    }
#pragma unroll
    for (int n = 0; n < 4; ++n) {
      const int rb = wcbase + n * 16 + (lane & 15);
      b[n] = *(const bf16x8*)(Bb + rb * 64 + ((j ^ (rb & 7)) << 3));
    }
    if (stage_sel == 1)      STAGE_A(stage_t, d ^ 1);
    else if (stage_sel == 2) STAGE_B(stage_t, d ^ 1);
    asm volatile("s_waitcnt lgkmcnt(0)" ::: "memory");
    __builtin_amdgcn_sched_barrier(0);
    __builtin_amdgcn_s_setprio(1);
#pragma unroll
    for (int n = 0; n < 4; ++n)
#pragma unroll
      for (int m = 0; m < 4; ++m)
        ac[m][n] = __builtin_amdgcn_mfma_f32_16x16x32_bf16(a[m], b[n], ac[m][n], 0, 0, 0);
    __builtin_amdgcn_s_setprio(0);
    __builtin_amdgcn_sched_barrier(0);
  };

  // prologue: tiles 0 (dbuf0) and 1 (dbuf1)
  STAGE_A(0, 0); STAGE_B(0, 0);
  STAGE_A(1, 1); STAGE_B(1, 1);

#pragma unroll 1
  for (int it = 0; it < 6; ++it) {
    const int t0 = it * 2;
    // ---- phase 1 (dbuf0, mh0, kk0) ; stage A(t0+1) -> dbuf1 (skip iter 0)
    asm volatile("s_waitcnt vmcnt(0)" ::: "memory");
    __builtin_amdgcn_s_barrier();
    QPHASE(0, acc0, 0, 0, (it > 0) ? 1 : 0, t0 + 1);
    // ---- phase 2 (dbuf0, mh0, kk1) ; stage B(t0+1) -> dbuf1
    __builtin_amdgcn_s_barrier();
    QPHASE(0, acc0, 0, 1, (it > 0) ? 2 : 0, t0 + 1);
    // ---- phase 3 (dbuf0, mh1, kk0)
    __builtin_amdgcn_s_barrier();
    QPHASE(0, acc1, 1, 0, 0, 0);
    // ---- phase 4 (dbuf0, mh1, kk1)
    __builtin_amdgcn_s_barrier();
    QPHASE(0, acc1, 1, 1, 0, 0);
    // ---- phase 5 (dbuf1, mh0, kk0) ; stage A(t0+2) -> dbuf0 (skip last iter)
    asm volatile("s_waitcnt vmcnt(0)" ::: "memory");
    __builtin_amdgcn_s_barrier();
    QPHASE(1, acc0, 0, 0, (it < 5) ? 1 : 0, t0 + 2);
    // ---- phase 6 (dbuf1, mh0, kk1) ; stage B(t0+2) -> dbuf0
    __builtin_amdgcn_s_barrier();
    QPHASE(1, acc0, 0, 1, (it < 5) ? 2 : 0, t0 + 2);
    // ---- phase 7 (dbuf1, mh1, kk0)
    __builtin_amdgcn_s_barrier();
    QPHASE(1, acc1, 1, 0, 0, 0);
    // ---- phase 8 (dbuf1, mh1, kk1)
    __builtin_amdgcn_s_barrier();
    QPHASE(1, acc1, 1, 1, 0, 0);
  }

  // epilogue: bias + relu + bf16 store
  const int lq = lane >> 4;
  const int lc = lane & 15;
#pragma unroll
  for (int n = 0; n < 4; ++n) {
    const int cg = col0 + wcbase + n * 16 + lc;
    const float bv = bias[cg];
#pragma unroll
    for (int m = 0; m < 4; ++m) {
      const int rg = row0 + wrbase + m * 16 + lq * 4;
#pragma unroll
      for (int r2 = 0; r2 < 4; ++r2) {
        float v0 = acc0[m][n][r2] + bv;
        H[(long)(rg + r2) * DIM + cg] = f2b(fmaxf(v0, 0.0f));
        float v1 = acc1[m][n][r2] + bv;
        H[(long)(rg + 64 + r2) * DIM + cg] = f2b(fmaxf(v1, 0.0f));
      }
    }
  }
}

// ---------------- K2: logits[n] = sum_k relu(h·Wa^T)·sigmoid(h·Wb^T)·Wc -------
__global__ __launch_bounds__(512)
void gate_kernel(const ushort* __restrict__ Hm, const ushort* __restrict__ Wa,
                 const ushort* __restrict__ Wb, const float* __restrict__ Wc,
                 float* __restrict__ logits) {
  __shared__ ushort Hs [128 * 64];
  __shared__ ushort Was[128 * 64];
  __shared__ ushort Wbs[128 * 64];
  const int tid  = threadIdx.x;
  const int wid  = tid >> 6;           // 0..7
  const int lane = tid & 63;
  const int row0 = blockIdx.x * 128;

  f32x4 fa[8] = {};
  f32x4 fb[8] = {};

  const int ld_r = lane >> 3;
  const int ld_c = (lane & 7) * 8;

  for (int k0 = 0; k0 < DIM; k0 += 64) {
    __syncthreads();
#pragma unroll
    for (int i = 0; i < 2; ++i) {
      const int ch = i * 8 + wid;      // 0..15
      const int r  = ch * 8 + ld_r;    // 0..127
      gload_lds16(Hm + (long)(row0 + r) * DIM + k0 + ld_c, Hs  + ch * 512);
      gload_lds16(Wa + (long)r * DIM        + k0 + ld_c, Was + ch * 512);
      gload_lds16(Wb + (long)r * DIM        + k0 + ld_c, Wbs + ch * 512);
    }
    __syncthreads();
#pragma unroll
    for (int kk = 0; kk < 2; ++kk) {
      const int kc = kk * 32 + (lane >> 4) * 8;
      bf16x8 h = *(const bf16x8*)(Hs + (wid * 16 + (lane & 15)) * 64 + kc);
#pragma unroll
      for (int n = 0; n < 8; ++n) {
        bf16x8 wa = *(const bf16x8*)(Was + (n * 16 + (lane & 15)) * 64 + kc);
        bf16x8 wb = *(const bf16x8*)(Wbs + (n * 16 + (lane & 15)) * 64 + kc);
        fa[n] = __builtin_amdgcn_mfma_f32_16x16x32_bf16(h, wa, fa[n], 0, 0, 0);
        fb[n] = __builtin_amdgcn_mfma_f32_16x16x32_bf16(h, wb, fb[n], 0, 0, 0);
      }
    }
  }

  const int lc = lane & 15;
  const int lq = lane >> 4;
  float g[4];
#pragma unroll
  for (int r = 0; r < 4; ++r) {
    float s = 0.f;
#pragma unroll
    for (int n = 0; n < 8; ++n) {
      float av = fmaxf(fa[n][r], 0.f);
      float sg = 1.f / (1.f + expf(-fb[n][r]));
      s += av * sg * Wc[n * 16 + lc];
    }
    s += __shfl_xor(s, 1);
    s += __shfl_xor(s, 2);
    s += __shfl_xor(s, 4);
    s += __shfl_xor(s, 8);
    g[r] = s;
  }
  if (lc == 0) {
    const int rbase = row0 + wid * 16 + lq * 4;
#pragma unroll
    for (int r = 0; r < 4; ++r) {
      const int nidx = rbase + r;
      if (nidx < NPTS) logits[nidx] = g[r];
    }
  }
}

// ---------------- K3a: per-block softmax partials (49 blocks x 1024) ----------
__global__ __launch_bounds__(1024)
void softmax_part_kernel(const float* __restrict__ logits, float* __restrict__ part2) {
  __shared__ float red[1024];
  const int tid = threadIdx.x;
  const int n = blockIdx.x * 1024 + tid;
  const float v = (n < NPTS) ? logits[n] : -1e30f;
  red[tid] = v; __syncthreads();
  for (int s = 512; s > 0; s >>= 1) {
    if (tid < s) red[tid] = fmaxf(red[tid], red[tid + s]);
    __syncthreads();
  }
  const float m = red[0];
  __syncthreads();
  red[tid] = (n < NPTS) ? expf(v - m) : 0.f;
  __syncthreads();
  for (int s = 512; s > 0; s >>= 1) {
    if (tid < s) red[tid] += red[tid + s];
    __syncthreads();
  }
  if (tid == 0) { part2[blockIdx.x * 2] = m; part2[blockIdx.x * 2 + 1] = red[0]; }
}

// ---------------- K3b: combine partials (1 wave, deterministic trees) ---------
__global__ void softmax_comb_kernel(const float* __restrict__ part2,
                                    float* __restrict__ stats) {
  const int l = threadIdx.x;           // 0..63
  float m = (l < NSMB) ? part2[l * 2]     : -1e30f;
  float s = (l < NSMB) ? part2[l * 2 + 1] : 0.f;
  float M = m;
  for (int o = 32; o > 0; o >>= 1) M = fmaxf(M, __shfl_xor(M, o));
  float sc = s * expf(m - M);          // padding: 0 * 0 = 0
  for (int o = 32; o > 0; o >>= 1) sc += __shfl_xor(sc, o);
  if (l == 0) { stats[0] = M; stats[1] = sc; }
}

// ---------------- K4: partial[b][d] = sum_{n in chunk} exp(l_n - m) * h[n][d] --
__global__ __launch_bounds__(192)
void weighted_partial_kernel(const ushort* __restrict__ Hm, const float* __restrict__ logits,
                             const float* __restrict__ stats, float* __restrict__ part) {
  __shared__ float w[128];
  const int b = blockIdx.x, tid = threadIdx.x;
  const int n0 = b * 128;
  if (tid < 128) {
    const int n = n0 + tid;
    w[tid] = (n < NPTS) ? expf(logits[n] - stats[0]) : 0.f;
  }
  __syncthreads();
  float4 acc = {0.f, 0.f, 0.f, 0.f};
  const ushort* hp = Hm + (long)n0 * DIM + tid * 4;
#pragma unroll 4
  for (int r = 0; r < 128; ++r) {
    const float wr = w[r];
    ushort4 v = *(const ushort4*)(hp + (long)r * DIM);
    acc.x += wr * b2f(v.x);
    acc.y += wr * b2f(v.y);
    acc.z += wr * b2f(v.z);
    acc.w += wr * b2f(v.w);
  }
  ((float4*)(part + (long)b * DIM))[tid] = acc;
}

// ---------------- K5: out[d] = (sum_b part[b][d]) / sum_exp --------------------
__global__ void final_reduce_kernel(const float* __restrict__ part,
                                    const float* __restrict__ stats,
                                    float* __restrict__ out) {
  const int c = blockIdx.x * blockDim.x + threadIdx.x;
  if (c >= DIM) return;
  float s = 0.f;
  for (int b = 0; b < NRB; ++b) s += part[(long)b * DIM + c];
  out[c] = s / stats[1];
}

extern "C" void kernel_launch(void* const* d_in, const int* in_sizes, int n_in,
                              void* d_out, int out_size, void* d_ws, size_t ws_size,
                              hipStream_t stream) {
  const float* x  = (const float*)d_in[0];
  const float* Wf = (const float*)d_in[1];
  const float* bf = (const float*)d_in[2];
  const float* Wa = (const float*)d_in[3];
  const float* Wb = (const float*)d_in[4];
  const float* Wc = (const float*)d_in[5];
  float* out = (float*)d_out;

  char* p = (char*)d_ws;
  ushort* xb  = (ushort*)p; p += (size_t)NPAD * DIM * 2;   // 77.1 MB
  ushort* hb  = (ushort*)p; p += (size_t)NPAD * DIM * 2;   // 77.1 MB
  ushort* wfb = (ushort*)p; p += (size_t)DIM * DIM * 2;
  ushort* wab = (ushort*)p; p += (size_t)DATT * DIM * 2;
  ushort* wbb = (ushort*)p; p += (size_t)DATT * DIM * 2;
  float* logits = (float*)p; p += (size_t)NPAD * 4;
  float* stats  = (float*)p; p += 256;
  float* part2  = (float*)p; p += 1024;
  float* part   = (float*)p; p += (size_t)NRB * DIM * 4;

  cvt8_kernel<<<2048, 256, 0, stream>>>(x, xb, NPTS * DIM / 8, NPAD * DIM / 8);
  cvt_weights_kernel<<<384, 256, 0, stream>>>(Wf, Wa, Wb, wfb, wab, wbb);

  gemm_h_kernel<<<196 * 3, 512, 0, stream>>>(xb, wfb, bf, hb);
  gate_kernel<<<NRB, 512, 0, stream>>>(hb, wab, wbb, Wc, logits);
  softmax_part_kernel<<<NSMB, 1024, 0, stream>>>(logits, part2);
  softmax_comb_kernel<<<1, 64, 0, stream>>>(part2, stats);
  weighted_partial_kernel<<<NRB, 192, 0, stream>>>(hb, logits, stats, part);
  final_reduce_kernel<<<3, 256, 0, stream>>>(part, stats, out);
}